// Round 18
// baseline (2063.426 us; speedup 1.0000x reference)
//
#include <hip/hip_runtime.h>
#include <math.h>

#define DD 64
#define SCAN_TPB 256
#define SCAN_EPT 8
#define SCAN_EPB (SCAN_TPB * SCAN_EPT)  // 2048 elements per block
#define NCHUNK 8                         // one target-range chunk per XCD (scatter)
#define HSLOTS 16384                     // LDS histogram slots (64 KB)
#define HBPR 8                           // blocks per range

typedef short bf16x8 __attribute__((ext_vector_type(8)));
typedef float f32x4 __attribute__((ext_vector_type(4)));

__device__ __forceinline__ float bf2f(unsigned short u) {
    return __uint_as_float(((unsigned)u) << 16);
}
__device__ __forceinline__ unsigned short f2bf(float x) {
    unsigned b = __float_as_uint(x);
    unsigned r = (b + 0x7fffu + ((b >> 16) & 1u)) >> 16;   // RNE
    return (unsigned short)r;
}
__device__ __forceinline__ int chunk_of(int t, int n) {
    return (int)(((long long)t * NCHUNK) / n);
}

// ============================ CSR build kernels ============================
// hist (R18): LDS-aggregated, ZERO global atomics — R15/R16/R17 all pinned at
// ~300us / 249MB writes (31B HBM write per global atomic, structure-invariant).
// Concat counter space [cntA | cntB] split into 16k-slot ranges; 8 blocks per
// range LDS-histogram their edge slice, flush via plain stores, then reduce.
// Scatter stays XCD-chunked (R8, proven).

__global__ void hist2_lds(int* __restrict__ hcp, const int* __restrict__ tgtA, int nA,
                          const int* __restrict__ tgtB, int E) {
    __shared__ int h[HSLOTS];
    int r = blockIdx.x / HBPR;
    int b = blockIdx.x % HBPR;
    int lo = r * HSLOTS;
    int hi = lo + HSLOTS;
    for (int i = threadIdx.x; i < HSLOTS; i += blockDim.x) h[i] = 0;
    __syncthreads();
    int baseB = nA + 1;
    bool needA = lo < baseB;
    bool needB = hi > baseB;
    int start = b * blockDim.x + threadIdx.x;
    int stride = HBPR * blockDim.x;
    if (needA && needB) {
        for (int e = start; e < E; e += stride) {
            int s = tgtA[e];
            if (s >= lo && s < hi) atomicAdd(&h[s - lo], 1);
            int s2 = baseB + tgtB[e];
            if (s2 >= lo && s2 < hi) atomicAdd(&h[s2 - lo], 1);
        }
    } else if (needA) {
        for (int e = start; e < E; e += stride) {
            int s = tgtA[e];
            if (s >= lo && s < hi) atomicAdd(&h[s - lo], 1);
        }
    } else {
        for (int e = start; e < E; e += stride) {
            int s2 = baseB + tgtB[e];
            if (s2 >= lo && s2 < hi) atomicAdd(&h[s2 - lo], 1);
        }
    }
    __syncthreads();
    int* dst = hcp + (size_t)blockIdx.x * HSLOTS;
    for (int i = threadIdx.x; i < HSLOTS; i += blockDim.x) dst[i] = h[i];
}

// cnt[s] = sum over HBPR per-block copies (full overwrite -> no memset needed)
__global__ void hist_reduce(int* __restrict__ cntA, int nA, int* __restrict__ cntB, int nB,
                            const int* __restrict__ hcp, int tot) {
    int s = blockIdx.x * blockDim.x + threadIdx.x;
    if (s >= tot) return;
    int r = s / HSLOTS;
    int off = s - r * HSLOTS;
    const int* base = hcp + (size_t)r * HBPR * HSLOTS + off;
    int sum = 0;
#pragma unroll
    for (int b = 0; b < HBPR; ++b) sum += base[(size_t)b * HSLOTS];
    if (s < nA + 1) cntA[s] = sum;
    else cntB[s - (nA + 1)] = sum;
}

__global__ void scatter_pairs_chunked(int2* __restrict__ pairs, int* __restrict__ cursor,
                                      const int* __restrict__ tgt, const int* __restrict__ src,
                                      const float* __restrict__ val, int E, int n) {
    int myc = blockIdx.x & (NCHUNK - 1);
    int sub = blockIdx.x >> 3;
    int nsub = gridDim.x >> 3;
    int start = sub * blockDim.x + threadIdx.x;
    int stride = nsub * blockDim.x;
    for (int e = start; e < E; e += stride) {
        int t_ = tgt[e];
        int c = chunk_of(t_, n);
        if (c == myc) {
            int2 pr;
            pr.x = src[e];
            pr.y = __float_as_int(val[e]);
            int p = atomicAdd(&cursor[t_], 1);
            pairs[p] = pr;
        }
    }
}

// ---- mini-CSR (batch-marked targets only) ----
__global__ void mark_kernel(int* __restrict__ mark, const int* __restrict__ idx, int n) {
    int g = blockIdx.x * blockDim.x + threadIdx.x;
    if (g < n) mark[idx[g]] = 1;
}

__global__ void hist_marked_kernel(int* __restrict__ cnt, const int* __restrict__ tgt,
                                   const int* __restrict__ mark, int E) {
    int g = blockIdx.x * blockDim.x + threadIdx.x;
    int stride = gridDim.x * blockDim.x;
    for (int e = g; e < E; e += stride) {
        int t_ = tgt[e];
        if (mark[t_]) atomicAdd(&cnt[t_], 1);
    }
}

__global__ void scatter_marked_kernel(int2* __restrict__ pairs, int* __restrict__ cursor,
                                      const int* __restrict__ tgt, const int* __restrict__ src,
                                      const float* __restrict__ val,
                                      const int* __restrict__ mark, int E) {
    int g = blockIdx.x * blockDim.x + threadIdx.x;
    int stride = gridDim.x * blockDim.x;
    for (int e = g; e < E; e += stride) {
        int t_ = tgt[e];
        if (mark[t_]) {
            int2 pr;
            pr.x = src[e];
            pr.y = __float_as_int(val[e]);
            int p = atomicAdd(&cursor[t_], 1);
            pairs[p] = pr;
        }
    }
}

// ---- scan primitives ----
__device__ __forceinline__ void scan_p1_body(int* blocksum, const int* cnt, int n, int lb,
                                             int t) {
    int base = lb * SCAN_EPB + t * SCAN_EPT;
    int s = 0;
#pragma unroll
    for (int k = 0; k < SCAN_EPT; ++k) {
        int i = base + k;
        if (i < n) s += cnt[i];
    }
#pragma unroll
    for (int o = 32; o >= 1; o >>= 1) s += __shfl_xor(s, o);
    __shared__ int ws_[4];
    if ((t & 63) == 0) ws_[t >> 6] = s;
    __syncthreads();
    if (t == 0) blocksum[lb] = ws_[0] + ws_[1] + ws_[2] + ws_[3];
}

__device__ __forceinline__ void scan_p2_body(int* blocksum, int nb, int* tot, int t) {
    __shared__ int sh[1024];
    int v = (t < nb) ? blocksum[t] : 0;
    sh[t] = v;
    __syncthreads();
    for (int o = 1; o < 1024; o <<= 1) {
        int x = (t >= o) ? sh[t - o] : 0;
        __syncthreads();
        sh[t] += x;
        __syncthreads();
    }
    if (t < nb) blocksum[t] = sh[t] - v;  // exclusive
    if (t == nb - 1) tot[0] = sh[t];
}

__device__ __forceinline__ void scan_p3_body(int* ptr, int* cursor, const int* cnt,
                                             const int* blockoff, int n, int lb, int t) {
    int base = lb * SCAN_EPB + t * SCAN_EPT;
    int vals[SCAN_EPT];
    int s = 0;
#pragma unroll
    for (int k = 0; k < SCAN_EPT; ++k) {
        int i = base + k;
        int c = (i < n) ? cnt[i] : 0;
        vals[k] = s;
        s += c;
    }
    int incl = s;
#pragma unroll
    for (int o = 1; o < 64; o <<= 1) {
        int x = __shfl_up(incl, o);
        if ((t & 63) >= o) incl += x;
    }
    __shared__ int wtot[4];
    if ((t & 63) == 63) wtot[t >> 6] = incl;
    __syncthreads();
    int woff = 0;
    int wv = t >> 6;
    for (int k = 0; k < 4; ++k)
        if (k < wv) woff += wtot[k];
    int texcl = incl - s + woff + blockoff[lb];
#pragma unroll
    for (int k = 0; k < SCAN_EPT; ++k) {
        int i = base + k;
        if (i < n) {
            int p = texcl + vals[k];
            ptr[i] = p;
            cursor[i] = p;
        }
    }
}

__global__ void scan_pass1(int* __restrict__ bsum, const int* __restrict__ cnt, int n) {
    scan_p1_body(bsum, cnt, n, blockIdx.x, threadIdx.x);
}
__global__ void scan_pass2(int* __restrict__ bsum, int nb, int* __restrict__ tot) {
    scan_p2_body(bsum, nb, tot, threadIdx.x);
}
__global__ void scan_pass3(int* __restrict__ ptr, int* __restrict__ cursor,
                           const int* __restrict__ cnt, const int* __restrict__ boff, int n) {
    scan_p3_body(ptr, cursor, cnt, boff, n, blockIdx.x, threadIdx.x);
}

__global__ void scan2_pass1(int* __restrict__ bsumA, const int* __restrict__ cntA, int nA,
                            int nbA,
                            int* __restrict__ bsumB, const int* __restrict__ cntB, int nB) {
    int b = blockIdx.x;
    if (b < nbA) scan_p1_body(bsumA, cntA, nA, b, threadIdx.x);
    else         scan_p1_body(bsumB, cntB, nB, b - nbA, threadIdx.x);
}
__global__ void scan2_pass2(int* __restrict__ bsumA, int nbA, int* __restrict__ totA,
                            int* __restrict__ bsumB, int nbB, int* __restrict__ totB) {
    if (blockIdx.x == 0) scan_p2_body(bsumA, nbA, totA, threadIdx.x);
    else                 scan_p2_body(bsumB, nbB, totB, threadIdx.x);
}
__global__ void scan2_pass3(int* __restrict__ ptrA, int* __restrict__ curA,
                            const int* __restrict__ cntA, const int* __restrict__ boffA,
                            int nA, int nbA,
                            int* __restrict__ ptrB, int* __restrict__ curB,
                            const int* __restrict__ cntB, const int* __restrict__ boffB,
                            int nB) {
    int b = blockIdx.x;
    if (b < nbA) scan_p3_body(ptrA, curA, cntA, boffA, nA, b, threadIdx.x);
    else         scan_p3_body(ptrB, curB, cntB, boffB, nB, b - nbA, threadIdx.x);
}

// ================== 2-row SpMM body (bf16 in, full rows) ==================
__device__ __forceinline__ void spmm2_rows(const unsigned short* __restrict__ inb,
                                           const int2* __restrict__ pairs,
                                           const int* __restrict__ ptr, int nrows,
                                           float* __restrict__ out,
                                           unsigned short* __restrict__ outb,
                                           int wp, int lane) {
    int w0 = wp * 2;
    if (w0 >= nrows) return;
    bool two = (w0 + 1 < nrows);
    int pA = ptr[w0];
    int endA = ptr[w0 + 1];
    int pB = two ? endA : 0;
    int endB = two ? ptr[w0 + 2] : 0;
    float accA = 0.f, accB = 0.f;
    while (endA - pA >= 8 && endB - pB >= 8) {
        int sA[8], sB[8];
        float vA[8], vB[8];
#pragma unroll
        for (int k = 0; k < 8; ++k) {
            int2 a = pairs[pA + k];
            int2 b = pairs[pB + k];
            sA[k] = __builtin_amdgcn_readfirstlane(a.x);
            vA[k] = __int_as_float(__builtin_amdgcn_readfirstlane(a.y));
            sB[k] = __builtin_amdgcn_readfirstlane(b.x);
            vB[k] = __int_as_float(__builtin_amdgcn_readfirstlane(b.y));
        }
#pragma unroll
        for (int k = 0; k < 8; ++k) {
            accA += vA[k] * bf2f(inb[(size_t)sA[k] * DD + lane]);
            accB += vB[k] * bf2f(inb[(size_t)sB[k] * DD + lane]);
        }
        pA += 8;
        pB += 8;
    }
    for (; pA + 8 <= endA; pA += 8) {
        int ss[8];
        float vv[8];
#pragma unroll
        for (int k = 0; k < 8; ++k) {
            int2 pr = pairs[pA + k];
            ss[k] = __builtin_amdgcn_readfirstlane(pr.x);
            vv[k] = __int_as_float(__builtin_amdgcn_readfirstlane(pr.y));
        }
#pragma unroll
        for (int k = 0; k < 8; ++k) accA += vv[k] * bf2f(inb[(size_t)ss[k] * DD + lane]);
    }
    for (; pA < endA; ++pA) {
        int2 pr = pairs[pA];
        int s = __builtin_amdgcn_readfirstlane(pr.x);
        accA += __int_as_float(__builtin_amdgcn_readfirstlane(pr.y)) *
                bf2f(inb[(size_t)s * DD + lane]);
    }
    for (; pB + 8 <= endB; pB += 8) {
        int ss[8];
        float vv[8];
#pragma unroll
        for (int k = 0; k < 8; ++k) {
            int2 pr = pairs[pB + k];
            ss[k] = __builtin_amdgcn_readfirstlane(pr.x);
            vv[k] = __int_as_float(__builtin_amdgcn_readfirstlane(pr.y));
        }
#pragma unroll
        for (int k = 0; k < 8; ++k) accB += vv[k] * bf2f(inb[(size_t)ss[k] * DD + lane]);
    }
    for (; pB < endB; ++pB) {
        int2 pr = pairs[pB];
        int s = __builtin_amdgcn_readfirstlane(pr.x);
        accB += __int_as_float(__builtin_amdgcn_readfirstlane(pr.y)) *
                bf2f(inb[(size_t)s * DD + lane]);
    }
    size_t offA = (size_t)w0 * DD + lane;
    if (out) {
        out[offA] = accA;
        if (two) out[offA + DD] = accB;
    }
    if (outb) {
        outb[offA] = f2bf(accA);
        if (two) outb[offA + DD] = f2bf(accB);
    }
}

__global__ void spmm2_kernel(const unsigned short* __restrict__ inb,
                             const int2* __restrict__ pairs, const int* __restrict__ ptr,
                             int nrows, float* __restrict__ out,
                             unsigned short* __restrict__ outb) {
    int wp = (int)(((unsigned)blockIdx.x * blockDim.x + threadIdx.x) >> 6);
    spmm2_rows(inb, pairs, ptr, nrows, out, outb, wp, threadIdx.x & 63);
}

__global__ void spmm2_dual_kernel(const unsigned short* __restrict__ inbA,
                                  const int2* __restrict__ pairsA, const int* __restrict__ ptrA,
                                  int nrowsA, unsigned short* __restrict__ outbA,
                                  const unsigned short* __restrict__ inbB,
                                  const int2* __restrict__ pairsB, const int* __restrict__ ptrB,
                                  int nrowsB, float* __restrict__ outB) {
    int nblkA = (nrowsA + 7) / 8;
    int blk = blockIdx.x;
    int lane = threadIdx.x & 63;
    int wvb = threadIdx.x >> 6;
    if (blk < nblkA) {
        spmm2_rows(inbA, pairsA, ptrA, nrowsA, nullptr, outbA, blk * 4 + wvb, lane);
    } else {
        blk -= nblkA;
        spmm2_rows(inbB, pairsB, ptrB, nrowsB, outB, nullptr, blk * 4 + wvb, lane);
    }
}

// ======================= unified segmented SpMM (flexible) =======================
__global__ void spmm_kernel(const float* __restrict__ inf, const unsigned short* __restrict__ inb,
                            const int2* __restrict__ pairs, const int* __restrict__ ptr,
                            int nrows, const int* __restrict__ rowidx,
                            float* __restrict__ out, unsigned short* __restrict__ outb,
                            const float* __restrict__ add1,
                            const float* __restrict__ add2f,
                            const unsigned short* __restrict__ add2b,
                            float scale1,
                            const float* __restrict__ in2f, const unsigned short* __restrict__ in2b,
                            float* __restrict__ out2, const float* __restrict__ addB,
                            float f, float scale2,
                            unsigned short* __restrict__ nrmOut, int nrmEvery) {
    int w = (int)(((unsigned)blockIdx.x * blockDim.x + threadIdx.x) >> 6);
    int lane = threadIdx.x & 63;
    if (w >= nrows) return;
    int r = rowidx ? rowidx[w] : w;
    int p = ptr[r];
    int end = ptr[r + 1];
    size_t outoff = (size_t)w * DD + lane;
    size_t nodeoff = (size_t)r * DD + lane;
    float acc = 0.f, acc2 = 0.f;
    const bool dual = (in2f != nullptr) || (in2b != nullptr);
    for (; p + 8 <= end; p += 8) {
        int ss[8];
        float vv[8];
#pragma unroll
        for (int k = 0; k < 8; ++k) {
            int2 pr = pairs[p + k];
            ss[k] = __builtin_amdgcn_readfirstlane(pr.x);
            vv[k] = __int_as_float(__builtin_amdgcn_readfirstlane(pr.y));
        }
        if (inb) {
#pragma unroll
            for (int k = 0; k < 8; ++k) acc += vv[k] * bf2f(inb[(size_t)ss[k] * DD + lane]);
        } else {
#pragma unroll
            for (int k = 0; k < 8; ++k) acc += vv[k] * inf[(size_t)ss[k] * DD + lane];
        }
        if (dual) {
            if (in2b) {
#pragma unroll
                for (int k = 0; k < 8; ++k) acc2 += vv[k] * bf2f(in2b[(size_t)ss[k] * DD + lane]);
            } else {
#pragma unroll
                for (int k = 0; k < 8; ++k) acc2 += vv[k] * in2f[(size_t)ss[k] * DD + lane];
            }
        }
    }
    for (; p < end; ++p) {
        int2 pr = pairs[p];
        int s = __builtin_amdgcn_readfirstlane(pr.x);
        float v = __int_as_float(__builtin_amdgcn_readfirstlane(pr.y));
        acc += v * (inb ? bf2f(inb[(size_t)s * DD + lane]) : inf[(size_t)s * DD + lane]);
        if (dual)
            acc2 += v * (in2b ? bf2f(in2b[(size_t)s * DD + lane]) : in2f[(size_t)s * DD + lane]);
    }
    float rr = acc;
    if (add1) rr += add1[nodeoff];
    if (add2f) rr += add2f[nodeoff];
    if (add2b) rr += bf2f(add2b[nodeoff]);
    rr *= scale1;
    if (out) out[outoff] = rr;
    if (outb) outb[outoff] = f2bf(rr);
    if (dual) {
        float r2 = acc2 + f * acc;
        if (addB) r2 += addB[nodeoff];
        out2[outoff] = r2 * scale2;
    }
    if (nrmOut && (nrmEvery == 1 || (w & 1) == 0)) {
        float sq = rr * rr;
#pragma unroll
        for (int o = 32; o >= 1; o >>= 1) sq += __shfl_xor(sq, o);
        nrmOut[(size_t)(w / nrmEvery) * DD + lane] = f2bf(rr * rsqrtf(sq + 1e-8f));
    }
}

// ============================= dense helpers ==============================

__global__ void f2bf3_kernel(unsigned short* __restrict__ o1, const float* __restrict__ i1,
                             long long n1,
                             unsigned short* __restrict__ o2, const float* __restrict__ i2,
                             long long n2,
                             unsigned short* __restrict__ o3, const float* __restrict__ i3,
                             long long n3) {
    long long g = (long long)blockIdx.x * blockDim.x + threadIdx.x;
    long long stride = (long long)gridDim.x * blockDim.x;
    long long tot = n1 + n2 + n3;
    for (long long t = g; t < tot; t += stride) {
        const float* ip;
        unsigned short* op;
        long long j = t;
        if (j < n1) { ip = i1; op = o1; }
        else if (j < n1 + n2) { j -= n1; ip = i2; op = o2; }
        else { j -= n1 + n2; ip = i3; op = o3; }
        float4 v = ((const float4*)ip)[j];
        ushort4 u;
        u.x = f2bf(v.x); u.y = f2bf(v.y); u.z = f2bf(v.z); u.w = f2bf(v.w);
        ((ushort4*)op)[j] = u;
    }
}

__global__ void gather_rows_bf16_kernel(float* __restrict__ raw,
                                        const unsigned short* __restrict__ src,
                                        const int* __restrict__ idx, int nrows) {
    int g = blockIdx.x * blockDim.x + threadIdx.x;
    if (g >= nrows * DD) return;
    int r = g >> 6;
    raw[g] = bf2f(src[(size_t)idx[r] * DD + (g & 63)]);
}

__global__ void batch_pred_kernel(const float* __restrict__ u1b, const float* __restrict__ u2b,
                                  const float* __restrict__ u3b,
                                  const float* __restrict__ b1b, const float* __restrict__ b2b,
                                  const float* __restrict__ b3b,
                                  const float* __restrict__ W1, const float* __restrict__ c1,
                                  const float* __restrict__ W2, const float* __restrict__ c2,
                                  const float* __restrict__ W3, const float* __restrict__ c3,
                                  float* __restrict__ acc, int nb) {
    int b = blockIdx.x;
    if (b >= nb) return;
    int d = threadIdx.x;
    float ud1 = u1b[(size_t)b * DD + d];
    float ud2 = u2b[(size_t)b * DD + d];
    float ud3 = u3b[(size_t)b * DD + d];
    float pred[2];
#pragma unroll
    for (int p = 0; p < 2; ++p) {
        size_t r = (size_t)(b * 2 + p) * DD + d;
        float s0 = ud1 * b1b[r];
        float s1 = ud2 * b2b[r];
        float s2 = ud3 * b3b[r];
#pragma unroll
        for (int o = 32; o >= 1; o >>= 1) {
            s0 += __shfl_xor(s0, o);
            s1 += __shfl_xor(s1, o);
            s2 += __shfl_xor(s2, o);
        }
        float t0 = tanhf(s0 * W1[0] + s1 * W1[1] + s2 * W1[2] + c1[0]);
        float t1 = tanhf(s0 * W1[3] + s1 * W1[4] + s2 * W1[5] + c1[1]);
        float t2 = tanhf(s0 * W1[6] + s1 * W1[7] + s2 * W1[8] + c1[2]);
        float g0 = tanhf(t0 * W2[0] + t1 * W2[1] + t2 * W2[2] + c2[0]);
        float g1 = tanhf(t0 * W2[3] + t1 * W2[4] + t2 * W2[5] + c2[1]);
        float g2 = tanhf(t0 * W2[6] + t1 * W2[7] + t2 * W2[8] + c2[2]);
        pred[p] = g0 * W3[0] + g1 * W3[1] + g2 * W3[2] + c3[0];
    }
    if (d == 0) {
        float x = pred[1] - pred[0];
        float sp = (x > 20.0f) ? x : log1pf(expf(x));
        unsafeAtomicAdd(acc, sp);
    }
}

// ===================== MFMA InfoNCE (both views, one launch) =====================
__global__ void nce_mfma_kernel(const unsigned short* __restrict__ A1,
                                const unsigned short* __restrict__ B1, float* __restrict__ acc1,
                                const unsigned short* __restrict__ A2,
                                const unsigned short* __restrict__ B2, float* __restrict__ acc2,
                                int n, float invtemp) {
    int nbv = n >> 4;
    const unsigned short* A;
    const unsigned short* B;
    float* accp;
    int blk = blockIdx.x;
    if (blk < nbv) { A = A1; B = B1; accp = acc1; }
    else           { blk -= nbv; A = A2; B = B2; accp = acc2; }
    int row0 = blk << 4;
    int wv = threadIdx.x >> 6, lane = threadIdx.x & 63;
    int li = lane & 15, lq = lane >> 4;

    const bf16x8* Ap = (const bf16x8*)(A + (size_t)(row0 + li) * DD + lq * 8);
    bf16x8 af0 = Ap[0];
    bf16x8 af1 = Ap[4];

    int qcols = n >> 2;
    int c0 = wv * qcols;
    int ntile = qcols >> 4;
    float m[4] = {-1e30f, -1e30f, -1e30f, -1e30f};
    float sm[4] = {0.f, 0.f, 0.f, 0.f};
    float dg[4] = {0.f, 0.f, 0.f, 0.f};
    for (int t = 0; t < ntile; ++t) {
        int colbase = c0 + (t << 4);
        const bf16x8* Bp = (const bf16x8*)(B + (size_t)(colbase + li) * DD + lq * 8);
        bf16x8 bf0 = Bp[0];
        bf16x8 bf1 = Bp[4];
        f32x4 z = {0.f, 0.f, 0.f, 0.f};
        f32x4 s = __builtin_amdgcn_mfma_f32_16x16x32_bf16(af0, bf0, z, 0, 0, 0);
        s = __builtin_amdgcn_mfma_f32_16x16x32_bf16(af1, bf1, s, 0, 0, 0);
        int col = colbase + li;
#pragma unroll
        for (int r = 0; r < 4; ++r) {
            float l = s[r] * invtemp;
            int row = row0 + (lq << 2) + r;
            if (col == row) dg[r] = l;
            float mn = fmaxf(m[r], l);
            sm[r] = sm[r] * __expf(m[r] - mn) + __expf(l - mn);
            m[r] = mn;
        }
    }
#pragma unroll
    for (int r = 0; r < 4; ++r) {
        float mm = m[r], ss = sm[r], dd = dg[r];
#pragma unroll
        for (int o = 1; o <= 8; o <<= 1) {
            float m2 = __shfl_xor(mm, o);
            float s2 = __shfl_xor(ss, o);
            float d2 = __shfl_xor(dd, o);
            float mn = fmaxf(mm, m2);
            ss = ss * __expf(mm - mn) + s2 * __expf(m2 - mn);
            mm = mn;
            dd += d2;
        }
        m[r] = mm; sm[r] = ss; dg[r] = dd;
    }
    __shared__ float pM[4][16], pS[4][16], pD[4][16];
    if (li == 0) {
#pragma unroll
        for (int r = 0; r < 4; ++r) {
            pM[wv][(lq << 2) + r] = m[r];
            pS[wv][(lq << 2) + r] = sm[r];
            pD[wv][(lq << 2) + r] = dg[r];
        }
    }
    __syncthreads();
    if (wv == 0 && lane < 16) {
        float mm = -1e30f, ss = 0.f, dd = 0.f;
#pragma unroll
        for (int q = 0; q < 4; ++q) {
            float mq = pM[q][lane], sq = pS[q][lane];
            dd += pD[q][lane];
            float mn = fmaxf(mm, mq);
            ss = ss * __expf(mm - mn) + sq * __expf(mq - mn);
            mm = mn;
        }
        float v = mm + logf(ss) - dd;
#pragma unroll
        for (int o = 1; o <= 8; o <<= 1) v += __shfl_xor(v, o);
        if (lane == 0) unsafeAtomicAdd(accp, v);
    }
}

__global__ void final_kernel(const float* __restrict__ acc, float* __restrict__ out,
                             float invn, float alpha) {
    out[0] = acc[0] * invn + alpha * invn * (acc[1] + acc[2]);
}

// ================================ driver ==================================
// ws proven >= 235.7 MB. This layout needs ~224 MB (incl. ~10 MB hist copies).

extern "C" void kernel_launch(void* const* d_in, const int* in_sizes, int n_in,
                              void* d_out, int out_size, void* d_ws, size_t ws_size,
                              hipStream_t stream) {
    const float* users_feat   = (const float*)d_in[0];
    const float* bundles_feat = (const float*)d_in[1];
    const float* items_feat   = (const float*)d_in[2];
    const float* W1 = (const float*)d_in[3];
    const float* c1 = (const float*)d_in[4];
    const float* W2 = (const float*)d_in[5];
    const float* c2 = (const float*)d_in[6];
    const float* W3 = (const float*)d_in[7];
    const float* c3 = (const float*)d_in[8];
    const float* ui_val = (const float*)d_in[9];
    const float* ub_val = (const float*)d_in[10];
    const float* bi_val = (const float*)d_in[11];
    const int* ui_row = (const int*)d_in[12];
    const int* ui_col = (const int*)d_in[13];
    const int* ub_row = (const int*)d_in[14];
    const int* ub_col = (const int*)d_in[15];
    const int* bi_row = (const int*)d_in[16];
    const int* bi_col = (const int*)d_in[17];
    const int* uidx = (const int*)d_in[18];
    const int* bidx = (const int*)d_in[19];

    const int U  = in_sizes[0] / DD;
    const int NB = in_sizes[1] / DD;
    const int I  = in_sizes[2] / DD;
    const int Eui = in_sizes[9];
    const int Eub = in_sizes[10];
    const int Ebi = in_sizes[11];
    const int BT = in_sizes[18];

    const size_t U64  = (size_t)U * DD;
    const size_t I64  = (size_t)I * DD;
    const size_t NB64 = (size_t)NB * DD;
    const size_t BT64 = (size_t)BT * DD;

    // ---------------- float buffers ----------------
    float* w = (float*)d_ws;
    size_t o = 0;
    float* RA  = w + o; o += I64;      // x1b -> y1b (f32)
    float* RB  = w + o; o += I64;      // i1 (f32)
    float* u3b = w + o; o += BT64;
    float* u1b = w + o; o += BT64;
    float* u2b = w + o; o += BT64;
    float* b1b = w + o; o += 2 * BT64;
    float* b2b = w + o; o += 2 * BT64;
    float* b3b = w + o; o += 2 * BT64;
    unsigned short* A1  = (unsigned short*)(w + o); o += BT64 / 2;
    unsigned short* A2  = (unsigned short*)(w + o); o += BT64 / 2;
    unsigned short* B1n = (unsigned short*)(w + o); o += BT64 / 2;
    unsigned short* B2n = (unsigned short*)(w + o); o += BT64 / 2;
    float* acc = w + o; o += 16;

    // ---------------- bf16 tables ----------------
    unsigned short* Ubf = (unsigned short*)(w + o); o += (U64 + 1) / 2;
    unsigned short* Ibf = (unsigned short*)(w + o); o += (I64 + 1) / 2;
    unsigned short* Bbf = (unsigned short*)(w + o); o += (NB64 + 1) / 2;
    unsigned short* Xbf = (unsigned short*)(w + o); o += (U64 + 1) / 2;   // x1a, then y1a

    // ---------------- int area ----------------
    int nmax = U; if (I > nmax) nmax = I; if (NB > nmax) nmax = NB;
    int emax = Eui; if (Eub > emax) emax = Eub; if (Ebi > emax) emax = Ebi;
    int maxSlots = U + I + 2;                       // largest concat hist space
    int NRa = (maxSlots + HSLOTS - 1) / HSLOTS;     // ranges to allocate
    int* ib = (int*)(w + o);
    size_t io_ = 0;
    int* cnt   = ib + io_; io_ += (size_t)nmax + 1;   // final counts / cursor A
    int* mark  = ib + io_; io_ += (size_t)NB + 1;     // adjacent to cnt (joint memset)
    int* cnt2  = ib + io_; io_ += (size_t)nmax + 1;   // final counts / cursor B
    int* bsum  = ib + io_; io_ += 1025;
    int* bsum2 = ib + io_; io_ += 1025;
    int* ptrA  = ib + io_; io_ += (size_t)nmax + 1;
    int* ptrB  = ib + io_; io_ += (size_t)nmax + 1;
    int* hcp   = ib + io_; io_ += (size_t)NRa * HBPR * HSLOTS;  // hist block copies
    io_ = (io_ + 3) & ~(size_t)3;
    int2* pairsA = (int2*)(ib + io_); io_ += (size_t)emax * 2;
    int2* pairsB = (int2*)(ib + io_); io_ += (size_t)emax * 2;

    const size_t zero_span = ((size_t)2 * (nmax + 1) + (NB + 1)) * sizeof(int);

    // fused dual build: LDS hist (no global atomics) + reduce; chunked scatters
    auto build2 = [&](const int* rowArr, int nA, const int* colArr, int nB_, const float* val,
                      int E) {
        int tot = nA + nB_ + 2;
        int NR = (tot + HSLOTS - 1) / HSLOTS;
        hist2_lds<<<NR * HBPR, 512, 0, stream>>>(hcp, rowArr, nA, colArr, E);
        hist_reduce<<<(tot + 255) / 256, 256, 0, stream>>>(cnt, nA, cnt2, nB_, hcp, tot);
        int nbA = (nA + SCAN_EPB - 1) / SCAN_EPB;
        int nbB = (nB_ + SCAN_EPB - 1) / SCAN_EPB;
        scan2_pass1<<<nbA + nbB, SCAN_TPB, 0, stream>>>(bsum, cnt, nA, nbA, bsum2, cnt2, nB_);
        scan2_pass2<<<2, 1024, 0, stream>>>(bsum, nbA, ptrA + nA, bsum2, nbB, ptrB + nB_);
        scan2_pass3<<<nbA + nbB, SCAN_TPB, 0, stream>>>(ptrA, cnt, cnt, bsum, nA, nbA,
                                                        ptrB, cnt2, cnt2, bsum2, nB_);
        scatter_pairs_chunked<<<8192, 256, 0, stream>>>(pairsA, cnt, rowArr, colArr, val,
                                                        E, nA);
        scatter_pairs_chunked<<<8192, 256, 0, stream>>>(pairsB, cnt2, colArr, rowArr, val,
                                                        E, nB_);
    };
    auto spmm = [&](const float* inf, const unsigned short* inb,
                    const int2* pairs, const int* ptr_, int nrows, const int* rowidx,
                    float* out, unsigned short* outb,
                    const float* add1, const float* add2f, const unsigned short* add2b,
                    float scale1,
                    const float* in2f, const unsigned short* in2b,
                    float* out2, const float* addB, float f, float scale2,
                    unsigned short* nrmOut, int nrmEvery) {
        int blocks = (nrows + 3) / 4;
        spmm_kernel<<<blocks, 256, 0, stream>>>(inf, inb, pairs, ptr_, nrows, rowidx,
                                                out, outb, add1, add2f, add2b, scale1,
                                                in2f, in2b, out2, addB, f, scale2,
                                                nrmOut, nrmEvery);
    };
    const float k3 = 1.0f / 3.0f;
    const float* NF = nullptr;
    const unsigned short* NB16 = nullptr;

    // ---- bf16 table conversions (one launch) ----
    f2bf3_kernel<<<3072, 256, 0, stream>>>(Ubf, users_feat, (long long)(U64 / 4),
                                           Ibf, items_feat, (long long)(I64 / 4),
                                           Bbf, bundles_feat, (long long)(NB64 / 4));

    // ---- View 1 (u-i): fused build of both CSRs ----
    build2(ui_row, U, ui_col, I, ui_val, Eui);
    spmm2_kernel<<<(U + 7) / 8, 256, 0, stream>>>(Ibf, pairsA, ptrA, U, nullptr, Xbf); // x1a
    gather_rows_bf16_kernel<<<(BT * DD + 255) / 256, 256, 0, stream>>>(u3b, Xbf, uidx, BT);
    spmm(NF, Ubf, pairsB, ptrB, I, nullptr,
         RA, nullptr, NF, NF, NB16, 1.f,
         NF, Xbf, RB, items_feat, 1.f, k3,
         nullptr, 1);                                                         // x1b + i1
    spmm(RA, NB16, pairsA, ptrA, BT, uidx,
         u1b, nullptr, users_feat, NF, Xbf, k3, NF, NB16, nullptr, NF, 0.f, 1.f,
         A1, 1);                                                              // u1 batch + A1

    // ---- b1 + b3 via mini-CSR over batch-marked bundles ----
    hipMemsetAsync(cnt, 0, zero_span, stream);   // zeroes cnt + mark (+cnt2, harmless)
    mark_kernel<<<(2 * BT + 255) / 256, 256, 0, stream>>>(mark, bidx, 2 * BT);
    {
        int gb = (Ebi + 255) / 256; if (gb > 4096) gb = 4096;
        hist_marked_kernel<<<gb, 256, 0, stream>>>(cnt, bi_row, mark, Ebi);
        int nb_ = (NB + SCAN_EPB - 1) / SCAN_EPB;
        scan_pass1<<<nb_, SCAN_TPB, 0, stream>>>(bsum, cnt, NB);
        scan_pass2<<<1, 1024, 0, stream>>>(bsum, nb_, ptrA + NB);
        scan_pass3<<<nb_, SCAN_TPB, 0, stream>>>(ptrA, cnt, cnt, bsum, NB);
        scatter_marked_kernel<<<gb, 256, 0, stream>>>(pairsA, cnt, bi_row, bi_col,
                                                      bi_val, mark, Ebi);
    }
    spmm(RB, NB16, pairsA, ptrA, 2 * BT, bidx,
         b1b, nullptr, NF, NF, NB16, 1.f,
         NF, Ibf, b3b, NF, 0.f, 1.f,
         B1n, 2);                                                             // b1b + b3b + B1n

    // ---- View 2 (u-b): fused build, then y1a + y1b in one launch ----
    build2(ub_row, U, ub_col, NB, ub_val, Eub);
    {
        int nblk = (U + 7) / 8 + (NB + 7) / 8;
        spmm2_dual_kernel<<<nblk, 256, 0, stream>>>(Bbf, pairsA, ptrA, U, Xbf,   // y1a
                                                    Ubf, pairsB, ptrB, NB, RA);  // y1b
    }
    spmm(RA, NB16, pairsA, ptrA, BT, uidx,
         u2b, nullptr, users_feat, NF, Xbf, k3, NF, NB16, nullptr, NF, 0.f, 1.f,
         A2, 1);                                                              // u2 batch + A2
    spmm(NF, Xbf, pairsB, ptrB, 2 * BT, bidx,
         b2b, nullptr, bundles_feat, RA, NB16, k3, NF, NB16, nullptr, NF, 0.f, 1.f,
         B2n, 2);                                                             // b2 batch + B2n

    hipMemsetAsync(acc, 0, 4 * sizeof(float), stream);

    batch_pred_kernel<<<BT, 64, 0, stream>>>(u1b, u2b, u3b, b1b, b2b, b3b,
                                             W1, c1, W2, c2, W3, c3, acc, BT);

    nce_mfma_kernel<<<2 * (BT / 16), 256, 0, stream>>>(A1, A2, acc + 1,
                                                       B1n, B2n, acc + 2, BT, 4.0f);

    final_kernel<<<1, 1, 0, stream>>>(acc, (float*)d_out, 1.0f / (float)BT, 0.5f);
}

// Round 19
// 1874.962 us; speedup vs baseline: 1.1005x; 1.1005x over previous
//
#include <hip/hip_runtime.h>
#include <math.h>

#define DD 64
#define SCAN_TPB 256
#define SCAN_EPT 8
#define SCAN_EPB (SCAN_TPB * SCAN_EPT)  // 2048 elements per block
#define NCHUNK 8                         // one target-range chunk per XCD (scatter)

typedef short bf16x8 __attribute__((ext_vector_type(8)));
typedef float f32x4 __attribute__((ext_vector_type(4)));

__device__ __forceinline__ float bf2f(unsigned short u) {
    return __uint_as_float(((unsigned)u) << 16);
}
__device__ __forceinline__ unsigned short f2bf(float x) {
    unsigned b = __float_as_uint(x);
    unsigned r = (b + 0x7fffu + ((b >> 16) & 1u)) >> 16;   // RNE
    return (unsigned short)r;
}
__device__ __forceinline__ int chunk_of(int t, int n) {
    return (int)(((long long)t * NCHUNK) / n);
}

// ============================ CSR build kernels ============================
// Final config (best measured): plain single-pass dual hist (R16, 310us —
// global-atomic write-through floor, structure-invariant per R15/R17/R18) +
// FUSED dual XCD-chunked scatter (R13, one edge-array sweep for both sides;
// beat separate scatters 1887 vs 1905/1921).

__global__ void hist2_plain(int* __restrict__ cntA, const int* __restrict__ tgtA,
                            int* __restrict__ cntB, const int* __restrict__ tgtB, int E) {
    int g = blockIdx.x * blockDim.x + threadIdx.x;
    int stride = gridDim.x * blockDim.x;
    for (int e = g; e < E; e += stride) {
        atomicAdd(&cntA[tgtA[e]], 1);
        atomicAdd(&cntB[tgtB[e]], 1);
    }
}

__global__ void scatter2_chunked(int2* __restrict__ pairsA, int* __restrict__ curA, int nA,
                                 int2* __restrict__ pairsB, int* __restrict__ curB, int nB,
                                 const int* __restrict__ rowA, const int* __restrict__ colA,
                                 const float* __restrict__ val, int E) {
    int myc = blockIdx.x & (NCHUNK - 1);
    int sub = blockIdx.x >> 3;
    int nsub = gridDim.x >> 3;
    int start = sub * blockDim.x + threadIdx.x;
    int stride = nsub * blockDim.x;
    for (int e = start; e < E; e += stride) {
        int r = rowA[e];
        int ci = colA[e];
        bool mA = (chunk_of(r, nA) == myc);
        bool mB = (chunk_of(ci, nB) == myc);
        if (mA || mB) {
            int v = __float_as_int(val[e]);
            if (mA) {
                int p = atomicAdd(&curA[r], 1);
                int2 pr; pr.x = ci; pr.y = v;
                pairsA[p] = pr;
            }
            if (mB) {
                int q = atomicAdd(&curB[ci], 1);
                int2 pr; pr.x = r; pr.y = v;
                pairsB[q] = pr;
            }
        }
    }
}

// ---- mini-CSR (batch-marked targets only) ----
__global__ void mark_kernel(int* __restrict__ mark, const int* __restrict__ idx, int n) {
    int g = blockIdx.x * blockDim.x + threadIdx.x;
    if (g < n) mark[idx[g]] = 1;
}

__global__ void hist_marked_kernel(int* __restrict__ cnt, const int* __restrict__ tgt,
                                   const int* __restrict__ mark, int E) {
    int g = blockIdx.x * blockDim.x + threadIdx.x;
    int stride = gridDim.x * blockDim.x;
    for (int e = g; e < E; e += stride) {
        int t_ = tgt[e];
        if (mark[t_]) atomicAdd(&cnt[t_], 1);
    }
}

__global__ void scatter_marked_kernel(int2* __restrict__ pairs, int* __restrict__ cursor,
                                      const int* __restrict__ tgt, const int* __restrict__ src,
                                      const float* __restrict__ val,
                                      const int* __restrict__ mark, int E) {
    int g = blockIdx.x * blockDim.x + threadIdx.x;
    int stride = gridDim.x * blockDim.x;
    for (int e = g; e < E; e += stride) {
        int t_ = tgt[e];
        if (mark[t_]) {
            int2 pr;
            pr.x = src[e];
            pr.y = __float_as_int(val[e]);
            int p = atomicAdd(&cursor[t_], 1);
            pairs[p] = pr;
        }
    }
}

// ---- scan primitives ----
__device__ __forceinline__ void scan_p1_body(int* blocksum, const int* cnt, int n, int lb,
                                             int t) {
    int base = lb * SCAN_EPB + t * SCAN_EPT;
    int s = 0;
#pragma unroll
    for (int k = 0; k < SCAN_EPT; ++k) {
        int i = base + k;
        if (i < n) s += cnt[i];
    }
#pragma unroll
    for (int o = 32; o >= 1; o >>= 1) s += __shfl_xor(s, o);
    __shared__ int ws_[4];
    if ((t & 63) == 0) ws_[t >> 6] = s;
    __syncthreads();
    if (t == 0) blocksum[lb] = ws_[0] + ws_[1] + ws_[2] + ws_[3];
}

__device__ __forceinline__ void scan_p2_body(int* blocksum, int nb, int* tot, int t) {
    __shared__ int sh[1024];
    int v = (t < nb) ? blocksum[t] : 0;
    sh[t] = v;
    __syncthreads();
    for (int o = 1; o < 1024; o <<= 1) {
        int x = (t >= o) ? sh[t - o] : 0;
        __syncthreads();
        sh[t] += x;
        __syncthreads();
    }
    if (t < nb) blocksum[t] = sh[t] - v;  // exclusive
    if (t == nb - 1) tot[0] = sh[t];
}

__device__ __forceinline__ void scan_p3_body(int* ptr, int* cursor, const int* cnt,
                                             const int* blockoff, int n, int lb, int t) {
    int base = lb * SCAN_EPB + t * SCAN_EPT;
    int vals[SCAN_EPT];
    int s = 0;
#pragma unroll
    for (int k = 0; k < SCAN_EPT; ++k) {
        int i = base + k;
        int c = (i < n) ? cnt[i] : 0;
        vals[k] = s;
        s += c;
    }
    int incl = s;
#pragma unroll
    for (int o = 1; o < 64; o <<= 1) {
        int x = __shfl_up(incl, o);
        if ((t & 63) >= o) incl += x;
    }
    __shared__ int wtot[4];
    if ((t & 63) == 63) wtot[t >> 6] = incl;
    __syncthreads();
    int woff = 0;
    int wv = t >> 6;
    for (int k = 0; k < 4; ++k)
        if (k < wv) woff += wtot[k];
    int texcl = incl - s + woff + blockoff[lb];
#pragma unroll
    for (int k = 0; k < SCAN_EPT; ++k) {
        int i = base + k;
        if (i < n) {
            int p = texcl + vals[k];
            ptr[i] = p;
            cursor[i] = p;
        }
    }
}

__global__ void scan_pass1(int* __restrict__ bsum, const int* __restrict__ cnt, int n) {
    scan_p1_body(bsum, cnt, n, blockIdx.x, threadIdx.x);
}
__global__ void scan_pass2(int* __restrict__ bsum, int nb, int* __restrict__ tot) {
    scan_p2_body(bsum, nb, tot, threadIdx.x);
}
__global__ void scan_pass3(int* __restrict__ ptr, int* __restrict__ cursor,
                           const int* __restrict__ cnt, const int* __restrict__ boff, int n) {
    scan_p3_body(ptr, cursor, cnt, boff, n, blockIdx.x, threadIdx.x);
}

__global__ void scan2_pass1(int* __restrict__ bsumA, const int* __restrict__ cntA, int nA,
                            int nbA,
                            int* __restrict__ bsumB, const int* __restrict__ cntB, int nB) {
    int b = blockIdx.x;
    if (b < nbA) scan_p1_body(bsumA, cntA, nA, b, threadIdx.x);
    else         scan_p1_body(bsumB, cntB, nB, b - nbA, threadIdx.x);
}
__global__ void scan2_pass2(int* __restrict__ bsumA, int nbA, int* __restrict__ totA,
                            int* __restrict__ bsumB, int nbB, int* __restrict__ totB) {
    if (blockIdx.x == 0) scan_p2_body(bsumA, nbA, totA, threadIdx.x);
    else                 scan_p2_body(bsumB, nbB, totB, threadIdx.x);
}
__global__ void scan2_pass3(int* __restrict__ ptrA, int* __restrict__ curA,
                            const int* __restrict__ cntA, const int* __restrict__ boffA,
                            int nA, int nbA,
                            int* __restrict__ ptrB, int* __restrict__ curB,
                            const int* __restrict__ cntB, const int* __restrict__ boffB,
                            int nB) {
    int b = blockIdx.x;
    if (b < nbA) scan_p3_body(ptrA, curA, cntA, boffA, nA, b, threadIdx.x);
    else         scan_p3_body(ptrB, curB, cntB, boffB, nB, b - nbA, threadIdx.x);
}

// ================== 2-row SpMM body (bf16 in, full rows) ==================
__device__ __forceinline__ void spmm2_rows(const unsigned short* __restrict__ inb,
                                           const int2* __restrict__ pairs,
                                           const int* __restrict__ ptr, int nrows,
                                           float* __restrict__ out,
                                           unsigned short* __restrict__ outb,
                                           int wp, int lane) {
    int w0 = wp * 2;
    if (w0 >= nrows) return;
    bool two = (w0 + 1 < nrows);
    int pA = ptr[w0];
    int endA = ptr[w0 + 1];
    int pB = two ? endA : 0;
    int endB = two ? ptr[w0 + 2] : 0;
    float accA = 0.f, accB = 0.f;
    while (endA - pA >= 8 && endB - pB >= 8) {
        int sA[8], sB[8];
        float vA[8], vB[8];
#pragma unroll
        for (int k = 0; k < 8; ++k) {
            int2 a = pairs[pA + k];
            int2 b = pairs[pB + k];
            sA[k] = __builtin_amdgcn_readfirstlane(a.x);
            vA[k] = __int_as_float(__builtin_amdgcn_readfirstlane(a.y));
            sB[k] = __builtin_amdgcn_readfirstlane(b.x);
            vB[k] = __int_as_float(__builtin_amdgcn_readfirstlane(b.y));
        }
#pragma unroll
        for (int k = 0; k < 8; ++k) {
            accA += vA[k] * bf2f(inb[(size_t)sA[k] * DD + lane]);
            accB += vB[k] * bf2f(inb[(size_t)sB[k] * DD + lane]);
        }
        pA += 8;
        pB += 8;
    }
    for (; pA + 8 <= endA; pA += 8) {
        int ss[8];
        float vv[8];
#pragma unroll
        for (int k = 0; k < 8; ++k) {
            int2 pr = pairs[pA + k];
            ss[k] = __builtin_amdgcn_readfirstlane(pr.x);
            vv[k] = __int_as_float(__builtin_amdgcn_readfirstlane(pr.y));
        }
#pragma unroll
        for (int k = 0; k < 8; ++k) accA += vv[k] * bf2f(inb[(size_t)ss[k] * DD + lane]);
    }
    for (; pA < endA; ++pA) {
        int2 pr = pairs[pA];
        int s = __builtin_amdgcn_readfirstlane(pr.x);
        accA += __int_as_float(__builtin_amdgcn_readfirstlane(pr.y)) *
                bf2f(inb[(size_t)s * DD + lane]);
    }
    for (; pB + 8 <= endB; pB += 8) {
        int ss[8];
        float vv[8];
#pragma unroll
        for (int k = 0; k < 8; ++k) {
            int2 pr = pairs[pB + k];
            ss[k] = __builtin_amdgcn_readfirstlane(pr.x);
            vv[k] = __int_as_float(__builtin_amdgcn_readfirstlane(pr.y));
        }
#pragma unroll
        for (int k = 0; k < 8; ++k) accB += vv[k] * bf2f(inb[(size_t)ss[k] * DD + lane]);
    }
    for (; pB < endB; ++pB) {
        int2 pr = pairs[pB];
        int s = __builtin_amdgcn_readfirstlane(pr.x);
        accB += __int_as_float(__builtin_amdgcn_readfirstlane(pr.y)) *
                bf2f(inb[(size_t)s * DD + lane]);
    }
    size_t offA = (size_t)w0 * DD + lane;
    if (out) {
        out[offA] = accA;
        if (two) out[offA + DD] = accB;
    }
    if (outb) {
        outb[offA] = f2bf(accA);
        if (two) outb[offA + DD] = f2bf(accB);
    }
}

__global__ void spmm2_kernel(const unsigned short* __restrict__ inb,
                             const int2* __restrict__ pairs, const int* __restrict__ ptr,
                             int nrows, float* __restrict__ out,
                             unsigned short* __restrict__ outb) {
    int wp = (int)(((unsigned)blockIdx.x * blockDim.x + threadIdx.x) >> 6);
    spmm2_rows(inb, pairs, ptr, nrows, out, outb, wp, threadIdx.x & 63);
}

__global__ void spmm2_dual_kernel(const unsigned short* __restrict__ inbA,
                                  const int2* __restrict__ pairsA, const int* __restrict__ ptrA,
                                  int nrowsA, unsigned short* __restrict__ outbA,
                                  const unsigned short* __restrict__ inbB,
                                  const int2* __restrict__ pairsB, const int* __restrict__ ptrB,
                                  int nrowsB, float* __restrict__ outB) {
    int nblkA = (nrowsA + 7) / 8;
    int blk = blockIdx.x;
    int lane = threadIdx.x & 63;
    int wvb = threadIdx.x >> 6;
    if (blk < nblkA) {
        spmm2_rows(inbA, pairsA, ptrA, nrowsA, nullptr, outbA, blk * 4 + wvb, lane);
    } else {
        blk -= nblkA;
        spmm2_rows(inbB, pairsB, ptrB, nrowsB, outB, nullptr, blk * 4 + wvb, lane);
    }
}

// ======================= unified segmented SpMM (flexible) =======================
__global__ void spmm_kernel(const float* __restrict__ inf, const unsigned short* __restrict__ inb,
                            const int2* __restrict__ pairs, const int* __restrict__ ptr,
                            int nrows, const int* __restrict__ rowidx,
                            float* __restrict__ out, unsigned short* __restrict__ outb,
                            const float* __restrict__ add1,
                            const float* __restrict__ add2f,
                            const unsigned short* __restrict__ add2b,
                            float scale1,
                            const float* __restrict__ in2f, const unsigned short* __restrict__ in2b,
                            float* __restrict__ out2, const float* __restrict__ addB,
                            float f, float scale2,
                            unsigned short* __restrict__ nrmOut, int nrmEvery) {
    int w = (int)(((unsigned)blockIdx.x * blockDim.x + threadIdx.x) >> 6);
    int lane = threadIdx.x & 63;
    if (w >= nrows) return;
    int r = rowidx ? rowidx[w] : w;
    int p = ptr[r];
    int end = ptr[r + 1];
    size_t outoff = (size_t)w * DD + lane;
    size_t nodeoff = (size_t)r * DD + lane;
    float acc = 0.f, acc2 = 0.f;
    const bool dual = (in2f != nullptr) || (in2b != nullptr);
    for (; p + 8 <= end; p += 8) {
        int ss[8];
        float vv[8];
#pragma unroll
        for (int k = 0; k < 8; ++k) {
            int2 pr = pairs[p + k];
            ss[k] = __builtin_amdgcn_readfirstlane(pr.x);
            vv[k] = __int_as_float(__builtin_amdgcn_readfirstlane(pr.y));
        }
        if (inb) {
#pragma unroll
            for (int k = 0; k < 8; ++k) acc += vv[k] * bf2f(inb[(size_t)ss[k] * DD + lane]);
        } else {
#pragma unroll
            for (int k = 0; k < 8; ++k) acc += vv[k] * inf[(size_t)ss[k] * DD + lane];
        }
        if (dual) {
            if (in2b) {
#pragma unroll
                for (int k = 0; k < 8; ++k) acc2 += vv[k] * bf2f(in2b[(size_t)ss[k] * DD + lane]);
            } else {
#pragma unroll
                for (int k = 0; k < 8; ++k) acc2 += vv[k] * in2f[(size_t)ss[k] * DD + lane];
            }
        }
    }
    for (; p < end; ++p) {
        int2 pr = pairs[p];
        int s = __builtin_amdgcn_readfirstlane(pr.x);
        float v = __int_as_float(__builtin_amdgcn_readfirstlane(pr.y));
        acc += v * (inb ? bf2f(inb[(size_t)s * DD + lane]) : inf[(size_t)s * DD + lane]);
        if (dual)
            acc2 += v * (in2b ? bf2f(in2b[(size_t)s * DD + lane]) : in2f[(size_t)s * DD + lane]);
    }
    float rr = acc;
    if (add1) rr += add1[nodeoff];
    if (add2f) rr += add2f[nodeoff];
    if (add2b) rr += bf2f(add2b[nodeoff]);
    rr *= scale1;
    if (out) out[outoff] = rr;
    if (outb) outb[outoff] = f2bf(rr);
    if (dual) {
        float r2 = acc2 + f * acc;
        if (addB) r2 += addB[nodeoff];
        out2[outoff] = r2 * scale2;
    }
    if (nrmOut && (nrmEvery == 1 || (w & 1) == 0)) {
        float sq = rr * rr;
#pragma unroll
        for (int o = 32; o >= 1; o >>= 1) sq += __shfl_xor(sq, o);
        nrmOut[(size_t)(w / nrmEvery) * DD + lane] = f2bf(rr * rsqrtf(sq + 1e-8f));
    }
}

// ============================= dense helpers ==============================

__global__ void f2bf3_kernel(unsigned short* __restrict__ o1, const float* __restrict__ i1,
                             long long n1,
                             unsigned short* __restrict__ o2, const float* __restrict__ i2,
                             long long n2,
                             unsigned short* __restrict__ o3, const float* __restrict__ i3,
                             long long n3) {
    long long g = (long long)blockIdx.x * blockDim.x + threadIdx.x;
    long long stride = (long long)gridDim.x * blockDim.x;
    long long tot = n1 + n2 + n3;
    for (long long t = g; t < tot; t += stride) {
        const float* ip;
        unsigned short* op;
        long long j = t;
        if (j < n1) { ip = i1; op = o1; }
        else if (j < n1 + n2) { j -= n1; ip = i2; op = o2; }
        else { j -= n1 + n2; ip = i3; op = o3; }
        float4 v = ((const float4*)ip)[j];
        ushort4 u;
        u.x = f2bf(v.x); u.y = f2bf(v.y); u.z = f2bf(v.z); u.w = f2bf(v.w);
        ((ushort4*)op)[j] = u;
    }
}

__global__ void gather_rows_bf16_kernel(float* __restrict__ raw,
                                        const unsigned short* __restrict__ src,
                                        const int* __restrict__ idx, int nrows) {
    int g = blockIdx.x * blockDim.x + threadIdx.x;
    if (g >= nrows * DD) return;
    int r = g >> 6;
    raw[g] = bf2f(src[(size_t)idx[r] * DD + (g & 63)]);
}

__global__ void batch_pred_kernel(const float* __restrict__ u1b, const float* __restrict__ u2b,
                                  const float* __restrict__ u3b,
                                  const float* __restrict__ b1b, const float* __restrict__ b2b,
                                  const float* __restrict__ b3b,
                                  const float* __restrict__ W1, const float* __restrict__ c1,
                                  const float* __restrict__ W2, const float* __restrict__ c2,
                                  const float* __restrict__ W3, const float* __restrict__ c3,
                                  float* __restrict__ acc, int nb) {
    int b = blockIdx.x;
    if (b >= nb) return;
    int d = threadIdx.x;
    float ud1 = u1b[(size_t)b * DD + d];
    float ud2 = u2b[(size_t)b * DD + d];
    float ud3 = u3b[(size_t)b * DD + d];
    float pred[2];
#pragma unroll
    for (int p = 0; p < 2; ++p) {
        size_t r = (size_t)(b * 2 + p) * DD + d;
        float s0 = ud1 * b1b[r];
        float s1 = ud2 * b2b[r];
        float s2 = ud3 * b3b[r];
#pragma unroll
        for (int o = 32; o >= 1; o >>= 1) {
            s0 += __shfl_xor(s0, o);
            s1 += __shfl_xor(s1, o);
            s2 += __shfl_xor(s2, o);
        }
        float t0 = tanhf(s0 * W1[0] + s1 * W1[1] + s2 * W1[2] + c1[0]);
        float t1 = tanhf(s0 * W1[3] + s1 * W1[4] + s2 * W1[5] + c1[1]);
        float t2 = tanhf(s0 * W1[6] + s1 * W1[7] + s2 * W1[8] + c1[2]);
        float g0 = tanhf(t0 * W2[0] + t1 * W2[1] + t2 * W2[2] + c2[0]);
        float g1 = tanhf(t0 * W2[3] + t1 * W2[4] + t2 * W2[5] + c2[1]);
        float g2 = tanhf(t0 * W2[6] + t1 * W2[7] + t2 * W2[8] + c2[2]);
        pred[p] = g0 * W3[0] + g1 * W3[1] + g2 * W3[2] + c3[0];
    }
    if (d == 0) {
        float x = pred[1] - pred[0];
        float sp = (x > 20.0f) ? x : log1pf(expf(x));
        unsafeAtomicAdd(acc, sp);
    }
}

// ===================== MFMA InfoNCE (both views, one launch) =====================
__global__ void nce_mfma_kernel(const unsigned short* __restrict__ A1,
                                const unsigned short* __restrict__ B1, float* __restrict__ acc1,
                                const unsigned short* __restrict__ A2,
                                const unsigned short* __restrict__ B2, float* __restrict__ acc2,
                                int n, float invtemp) {
    int nbv = n >> 4;
    const unsigned short* A;
    const unsigned short* B;
    float* accp;
    int blk = blockIdx.x;
    if (blk < nbv) { A = A1; B = B1; accp = acc1; }
    else           { blk -= nbv; A = A2; B = B2; accp = acc2; }
    int row0 = blk << 4;
    int wv = threadIdx.x >> 6, lane = threadIdx.x & 63;
    int li = lane & 15, lq = lane >> 4;

    const bf16x8* Ap = (const bf16x8*)(A + (size_t)(row0 + li) * DD + lq * 8);
    bf16x8 af0 = Ap[0];
    bf16x8 af1 = Ap[4];

    int qcols = n >> 2;
    int c0 = wv * qcols;
    int ntile = qcols >> 4;
    float m[4] = {-1e30f, -1e30f, -1e30f, -1e30f};
    float sm[4] = {0.f, 0.f, 0.f, 0.f};
    float dg[4] = {0.f, 0.f, 0.f, 0.f};
    for (int t = 0; t < ntile; ++t) {
        int colbase = c0 + (t << 4);
        const bf16x8* Bp = (const bf16x8*)(B + (size_t)(colbase + li) * DD + lq * 8);
        bf16x8 bf0 = Bp[0];
        bf16x8 bf1 = Bp[4];
        f32x4 z = {0.f, 0.f, 0.f, 0.f};
        f32x4 s = __builtin_amdgcn_mfma_f32_16x16x32_bf16(af0, bf0, z, 0, 0, 0);
        s = __builtin_amdgcn_mfma_f32_16x16x32_bf16(af1, bf1, s, 0, 0, 0);
        int col = colbase + li;
#pragma unroll
        for (int r = 0; r < 4; ++r) {
            float l = s[r] * invtemp;
            int row = row0 + (lq << 2) + r;
            if (col == row) dg[r] = l;
            float mn = fmaxf(m[r], l);
            sm[r] = sm[r] * __expf(m[r] - mn) + __expf(l - mn);
            m[r] = mn;
        }
    }
#pragma unroll
    for (int r = 0; r < 4; ++r) {
        float mm = m[r], ss = sm[r], dd = dg[r];
#pragma unroll
        for (int o = 1; o <= 8; o <<= 1) {
            float m2 = __shfl_xor(mm, o);
            float s2 = __shfl_xor(ss, o);
            float d2 = __shfl_xor(dd, o);
            float mn = fmaxf(mm, m2);
            ss = ss * __expf(mm - mn) + s2 * __expf(m2 - mn);
            mm = mn;
            dd += d2;
        }
        m[r] = mm; sm[r] = ss; dg[r] = dd;
    }
    __shared__ float pM[4][16], pS[4][16], pD[4][16];
    if (li == 0) {
#pragma unroll
        for (int r = 0; r < 4; ++r) {
            pM[wv][(lq << 2) + r] = m[r];
            pS[wv][(lq << 2) + r] = sm[r];
            pD[wv][(lq << 2) + r] = dg[r];
        }
    }
    __syncthreads();
    if (wv == 0 && lane < 16) {
        float mm = -1e30f, ss = 0.f, dd = 0.f;
#pragma unroll
        for (int q = 0; q < 4; ++q) {
            float mq = pM[q][lane], sq = pS[q][lane];
            dd += pD[q][lane];
            float mn = fmaxf(mm, mq);
            ss = ss * __expf(mm - mn) + sq * __expf(mq - mn);
            mm = mn;
        }
        float v = mm + logf(ss) - dd;
#pragma unroll
        for (int o = 1; o <= 8; o <<= 1) v += __shfl_xor(v, o);
        if (lane == 0) unsafeAtomicAdd(accp, v);
    }
}

__global__ void final_kernel(const float* __restrict__ acc, float* __restrict__ out,
                             float invn, float alpha) {
    out[0] = acc[0] * invn + alpha * invn * (acc[1] + acc[2]);
}

// ================================ driver ==================================
// ws proven >= 235.7 MB. This layout needs ~204 MB.

extern "C" void kernel_launch(void* const* d_in, const int* in_sizes, int n_in,
                              void* d_out, int out_size, void* d_ws, size_t ws_size,
                              hipStream_t stream) {
    const float* users_feat   = (const float*)d_in[0];
    const float* bundles_feat = (const float*)d_in[1];
    const float* items_feat   = (const float*)d_in[2];
    const float* W1 = (const float*)d_in[3];
    const float* c1 = (const float*)d_in[4];
    const float* W2 = (const float*)d_in[5];
    const float* c2 = (const float*)d_in[6];
    const float* W3 = (const float*)d_in[7];
    const float* c3 = (const float*)d_in[8];
    const float* ui_val = (const float*)d_in[9];
    const float* ub_val = (const float*)d_in[10];
    const float* bi_val = (const float*)d_in[11];
    const int* ui_row = (const int*)d_in[12];
    const int* ui_col = (const int*)d_in[13];
    const int* ub_row = (const int*)d_in[14];
    const int* ub_col = (const int*)d_in[15];
    const int* bi_row = (const int*)d_in[16];
    const int* bi_col = (const int*)d_in[17];
    const int* uidx = (const int*)d_in[18];
    const int* bidx = (const int*)d_in[19];

    const int U  = in_sizes[0] / DD;
    const int NB = in_sizes[1] / DD;
    const int I  = in_sizes[2] / DD;
    const int Eui = in_sizes[9];
    const int Eub = in_sizes[10];
    const int Ebi = in_sizes[11];
    const int BT = in_sizes[18];

    const size_t U64  = (size_t)U * DD;
    const size_t I64  = (size_t)I * DD;
    const size_t NB64 = (size_t)NB * DD;
    const size_t BT64 = (size_t)BT * DD;

    // ---------------- float buffers ----------------
    float* w = (float*)d_ws;
    size_t o = 0;
    float* RA  = w + o; o += I64;      // x1b -> y1b (f32)
    float* RB  = w + o; o += I64;      // i1 (f32)
    float* u3b = w + o; o += BT64;
    float* u1b = w + o; o += BT64;
    float* u2b = w + o; o += BT64;
    float* b1b = w + o; o += 2 * BT64;
    float* b2b = w + o; o += 2 * BT64;
    float* b3b = w + o; o += 2 * BT64;
    unsigned short* A1  = (unsigned short*)(w + o); o += BT64 / 2;
    unsigned short* A2  = (unsigned short*)(w + o); o += BT64 / 2;
    unsigned short* B1n = (unsigned short*)(w + o); o += BT64 / 2;
    unsigned short* B2n = (unsigned short*)(w + o); o += BT64 / 2;
    float* acc = w + o; o += 16;

    // ---------------- bf16 tables ----------------
    unsigned short* Ubf = (unsigned short*)(w + o); o += (U64 + 1) / 2;
    unsigned short* Ibf = (unsigned short*)(w + o); o += (I64 + 1) / 2;
    unsigned short* Bbf = (unsigned short*)(w + o); o += (NB64 + 1) / 2;
    unsigned short* Xbf = (unsigned short*)(w + o); o += (U64 + 1) / 2;   // x1a, then y1a

    // ---------------- int area ----------------
    int nmax = U; if (I > nmax) nmax = I; if (NB > nmax) nmax = NB;
    int emax = Eui; if (Eub > emax) emax = Eub; if (Ebi > emax) emax = Ebi;
    int* ib = (int*)(w + o);
    size_t io_ = 0;
    int* cnt   = ib + io_; io_ += (size_t)nmax + 1;   // counts / cursor A
    int* mark  = ib + io_; io_ += (size_t)NB + 1;     // adjacent to cnt (joint memset)
    int* cnt2  = ib + io_; io_ += (size_t)nmax + 1;   // counts / cursor B
    int* bsum  = ib + io_; io_ += 1025;
    int* bsum2 = ib + io_; io_ += 1025;
    int* ptrA  = ib + io_; io_ += (size_t)nmax + 1;
    int* ptrB  = ib + io_; io_ += (size_t)nmax + 1;
    io_ = (io_ + 3) & ~(size_t)3;
    int2* pairsA = (int2*)(ib + io_); io_ += (size_t)emax * 2;
    int2* pairsB = (int2*)(ib + io_); io_ += (size_t)emax * 2;

    const size_t zero_span = ((size_t)2 * (nmax + 1) + (NB + 1)) * sizeof(int);

    // fused dual build: plain hist (atomic floor) + fused dual chunked scatter
    auto build2 = [&](const int* rowArr, int nA, const int* colArr, int nB_, const float* val,
                      int E) {
        hipMemsetAsync(cnt, 0, zero_span, stream);
        int gb = (E + 255) / 256; if (gb > 4096) gb = 4096;
        hist2_plain<<<gb, 256, 0, stream>>>(cnt, rowArr, cnt2, colArr, E);
        int nbA = (nA + SCAN_EPB - 1) / SCAN_EPB;
        int nbB = (nB_ + SCAN_EPB - 1) / SCAN_EPB;
        scan2_pass1<<<nbA + nbB, SCAN_TPB, 0, stream>>>(bsum, cnt, nA, nbA, bsum2, cnt2, nB_);
        scan2_pass2<<<2, 1024, 0, stream>>>(bsum, nbA, ptrA + nA, bsum2, nbB, ptrB + nB_);
        scan2_pass3<<<nbA + nbB, SCAN_TPB, 0, stream>>>(ptrA, cnt, cnt, bsum, nA, nbA,
                                                        ptrB, cnt2, cnt2, bsum2, nB_);
        scatter2_chunked<<<8192, 256, 0, stream>>>(pairsA, cnt, nA, pairsB, cnt2, nB_,
                                                   rowArr, colArr, val, E);
    };
    auto spmm = [&](const float* inf, const unsigned short* inb,
                    const int2* pairs, const int* ptr_, int nrows, const int* rowidx,
                    float* out, unsigned short* outb,
                    const float* add1, const float* add2f, const unsigned short* add2b,
                    float scale1,
                    const float* in2f, const unsigned short* in2b,
                    float* out2, const float* addB, float f, float scale2,
                    unsigned short* nrmOut, int nrmEvery) {
        int blocks = (nrows + 3) / 4;
        spmm_kernel<<<blocks, 256, 0, stream>>>(inf, inb, pairs, ptr_, nrows, rowidx,
                                                out, outb, add1, add2f, add2b, scale1,
                                                in2f, in2b, out2, addB, f, scale2,
                                                nrmOut, nrmEvery);
    };
    const float k3 = 1.0f / 3.0f;
    const float* NF = nullptr;
    const unsigned short* NB16 = nullptr;

    // ---- bf16 table conversions (one launch) ----
    f2bf3_kernel<<<3072, 256, 0, stream>>>(Ubf, users_feat, (long long)(U64 / 4),
                                           Ibf, items_feat, (long long)(I64 / 4),
                                           Bbf, bundles_feat, (long long)(NB64 / 4));

    // ---- View 1 (u-i): fused build of both CSRs ----
    build2(ui_row, U, ui_col, I, ui_val, Eui);
    spmm2_kernel<<<(U + 7) / 8, 256, 0, stream>>>(Ibf, pairsA, ptrA, U, nullptr, Xbf); // x1a
    gather_rows_bf16_kernel<<<(BT * DD + 255) / 256, 256, 0, stream>>>(u3b, Xbf, uidx, BT);
    spmm(NF, Ubf, pairsB, ptrB, I, nullptr,
         RA, nullptr, NF, NF, NB16, 1.f,
         NF, Xbf, RB, items_feat, 1.f, k3,
         nullptr, 1);                                                         // x1b + i1
    spmm(RA, NB16, pairsA, ptrA, BT, uidx,
         u1b, nullptr, users_feat, NF, Xbf, k3, NF, NB16, nullptr, NF, 0.f, 1.f,
         A1, 1);                                                              // u1 batch + A1

    // ---- b1 + b3 via mini-CSR over batch-marked bundles ----
    hipMemsetAsync(cnt, 0, zero_span, stream);   // zeroes cnt + mark (+cnt2, harmless)
    mark_kernel<<<(2 * BT + 255) / 256, 256, 0, stream>>>(mark, bidx, 2 * BT);
    {
        int gb = (Ebi + 255) / 256; if (gb > 4096) gb = 4096;
        hist_marked_kernel<<<gb, 256, 0, stream>>>(cnt, bi_row, mark, Ebi);
        int nb_ = (NB + SCAN_EPB - 1) / SCAN_EPB;
        scan_pass1<<<nb_, SCAN_TPB, 0, stream>>>(bsum, cnt, NB);
        scan_pass2<<<1, 1024, 0, stream>>>(bsum, nb_, ptrA + NB);
        scan_pass3<<<nb_, SCAN_TPB, 0, stream>>>(ptrA, cnt, cnt, bsum, NB);
        scatter_marked_kernel<<<gb, 256, 0, stream>>>(pairsA, cnt, bi_row, bi_col,
                                                      bi_val, mark, Ebi);
    }
    spmm(RB, NB16, pairsA, ptrA, 2 * BT, bidx,
         b1b, nullptr, NF, NF, NB16, 1.f,
         NF, Ibf, b3b, NF, 0.f, 1.f,
         B1n, 2);                                                             // b1b + b3b + B1n

    // ---- View 2 (u-b): fused build, then y1a + y1b in one launch ----
    build2(ub_row, U, ub_col, NB, ub_val, Eub);
    {
        int nblk = (U + 7) / 8 + (NB + 7) / 8;
        spmm2_dual_kernel<<<nblk, 256, 0, stream>>>(Bbf, pairsA, ptrA, U, Xbf,   // y1a
                                                    Ubf, pairsB, ptrB, NB, RA);  // y1b
    }
    spmm(RA, NB16, pairsA, ptrA, BT, uidx,
         u2b, nullptr, users_feat, NF, Xbf, k3, NF, NB16, nullptr, NF, 0.f, 1.f,
         A2, 1);                                                              // u2 batch + A2
    spmm(NF, Xbf, pairsB, ptrB, 2 * BT, bidx,
         b2b, nullptr, bundles_feat, RA, NB16, k3, NF, NB16, nullptr, NF, 0.f, 1.f,
         B2n, 2);                                                             // b2 batch + B2n

    hipMemsetAsync(acc, 0, 4 * sizeof(float), stream);

    batch_pred_kernel<<<BT, 64, 0, stream>>>(u1b, u2b, u3b, b1b, b2b, b3b,
                                             W1, c1, W2, c2, W3, c3, acc, BT);

    nce_mfma_kernel<<<2 * (BT / 16), 256, 0, stream>>>(A1, A2, acc + 1,
                                                       B1n, B2n, acc + 2, BT, 4.0f);

    final_kernel<<<1, 1, 0, stream>>>(acc, (float*)d_out, 1.0f / (float)BT, 0.5f);
}